// Round 13
// baseline (201.067 us; speedup 1.0000x reference)
//
#include <hip/hip_runtime.h>
#include <hip/hip_bf16.h>
#include <math.h>

#define L_SEQ 512
#define DM 768
#define DI 1536
#define DS 64
#define DC 4
#define DR 48
#define NBC 128          // B/C output columns (2*DS), interleaved B0C0B1C1...
#define NP2 (NBC + DI)   // 1664: proj2 output width (B/C | dt)
#define NCF 8            // fused-scan chunks
#define TCF 64           // steps per fused chunk

typedef __attribute__((ext_vector_type(8))) short short8;
typedef __attribute__((ext_vector_type(4))) float float4v;

// prep job partition (1024-elem cvt jobs + LN rows + Weff tiles)
#define J_LN 512
#define J_WI (2 * DI * DM / 1024)   // 2304
#define J_WBC (NBC * DI / 1024)     // 192
#define J_WO (DM * DI / 1024)       // 1152
#define J_WEFF ((DI / 64) * (DI / 64))  // 576
#define PREP_GRID (J_LN + J_WI + J_WBC + J_WO + J_WEFF)  // 4736

// ---------------------------------------------------------------------------
// helpers
// ---------------------------------------------------------------------------
__device__ __forceinline__ float bp_add(float p, int addr) {
  return p + __int_as_float(__builtin_amdgcn_ds_bpermute(addr, __float_as_int(p)));
}
__device__ __forceinline__ float lane_read(float v, int t) {
  return __int_as_float(__builtin_amdgcn_readlane(__float_as_int(v), t));
}
__device__ __forceinline__ short f2bf(float v) {
  __hip_bfloat16 h = __float2bfloat16(v);
  return *reinterpret_cast<short*>(&h);
}
__device__ __forceinline__ short8 cvt8f(const float* p, bool valid) {
  float4 u = *(const float4*)(p);
  float4 v = *(const float4*)(p + 4);
  short8 r;
  r[0] = f2bf(u.x); r[1] = f2bf(u.y); r[2] = f2bf(u.z); r[3] = f2bf(u.w);
  r[4] = f2bf(v.x); r[5] = f2bf(v.y); r[6] = f2bf(v.z); r[7] = f2bf(v.w);
  if (!valid) r = (short8)0;
  return r;
}
__device__ __forceinline__ void cvt_blk(const float* __restrict__ s,
                                        short* __restrict__ d, int b) {
  int i = b * 1024 + threadIdx.x * 4;
  float4 v = *(const float4*)(s + i);
  short4 o; o.x = f2bf(v.x); o.y = f2bf(v.y); o.z = f2bf(v.z); o.w = f2bf(v.w);
  *(short4*)(d + i) = o;
}

// ---------------------------------------------------------------------------
// 32x32-tile GEMM core with 4-wave intra-block K-split + LDS reduce
// (verified R9/R10). Caller coords: lrow=(w&1)*16+(lane>>4)*4,
// lcol=(w>>1)*16+(lane&15).
// ---------------------------------------------------------------------------
__device__ __forceinline__ float4v gemm32_core(
    const short* __restrict__ A, int lda, const short* __restrict__ B, int ldb,
    int K, int bx, int by, int lane, int w, float4v* red) {
  int ks = K >> 2;
  int kbeg = w * ks;
  int fr = lane & 15, koff = (lane >> 4) * 8;
  int m0 = by * 32, n0 = bx * 32;
  const short* pA0 = A + (size_t)(m0 + fr) * lda + koff + kbeg;
  const short* pA1 = pA0 + (size_t)16 * lda;
  const short* pB0 = B + (size_t)(n0 + fr) * ldb + koff + kbeg;
  const short* pB1 = pB0 + (size_t)16 * ldb;
  float4v acc00 = (float4v){0.f,0.f,0.f,0.f}, acc01 = acc00;
  float4v acc10 = acc00, acc11 = acc00;
  short8 a0A = *(const short8*)(pA0);      short8 a1A = *(const short8*)(pA1);
  short8 b0A = *(const short8*)(pB0);      short8 b1A = *(const short8*)(pB1);
  short8 a0B = *(const short8*)(pA0 + 32); short8 a1B = *(const short8*)(pA1 + 32);
  short8 b0B = *(const short8*)(pB0 + 32); short8 b1B = *(const short8*)(pB1 + 32);
  for (int k0 = 0; k0 < ks; k0 += 64) {
    short8 ca0 = a0A, ca1 = a1A, cb0 = b0A, cb1 = b1A;
    short8 da0 = a0B, da1 = a1B, db0 = b0B, db1 = b1B;
    int nA = k0 + 64; if (nA >= ks) nA = 0;
    int nB = k0 + 96; if (nB >= ks) nB = 32;
    a0A = *(const short8*)(pA0 + nA); a1A = *(const short8*)(pA1 + nA);
    b0A = *(const short8*)(pB0 + nA); b1A = *(const short8*)(pB1 + nA);
    a0B = *(const short8*)(pA0 + nB); a1B = *(const short8*)(pA1 + nB);
    b0B = *(const short8*)(pB0 + nB); b1B = *(const short8*)(pB1 + nB);
    acc00 = __builtin_amdgcn_mfma_f32_16x16x32_bf16(ca0, cb0, acc00, 0, 0, 0);
    acc01 = __builtin_amdgcn_mfma_f32_16x16x32_bf16(ca0, cb1, acc01, 0, 0, 0);
    acc10 = __builtin_amdgcn_mfma_f32_16x16x32_bf16(ca1, cb0, acc10, 0, 0, 0);
    acc11 = __builtin_amdgcn_mfma_f32_16x16x32_bf16(ca1, cb1, acc11, 0, 0, 0);
    acc00 = __builtin_amdgcn_mfma_f32_16x16x32_bf16(da0, db0, acc00, 0, 0, 0);
    acc01 = __builtin_amdgcn_mfma_f32_16x16x32_bf16(da0, db1, acc01, 0, 0, 0);
    acc10 = __builtin_amdgcn_mfma_f32_16x16x32_bf16(da1, db0, acc10, 0, 0, 0);
    acc11 = __builtin_amdgcn_mfma_f32_16x16x32_bf16(da1, db1, acc11, 0, 0, 0);
  }
  red[(w * 4 + 0) * 64 + lane] = acc00;
  red[(w * 4 + 1) * 64 + lane] = acc01;
  red[(w * 4 + 2) * 64 + lane] = acc10;
  red[(w * 4 + 3) * 64 + lane] = acc11;
  __syncthreads();
  float4v v = red[(0 * 4 + w) * 64 + lane];
  v = v + red[(1 * 4 + w) * 64 + lane];
  v = v + red[(2 * 4 + w) * 64 + lane];
  v = v + red[(3 * 4 + w) * 64 + lane];
  return v;
}

// ---------------------------------------------------------------------------
// 32x32 transposed store (verified R10).
// ---------------------------------------------------------------------------
__device__ __forceinline__ void trans_store32(float* t, float4v v,
                                              int lrow, int lcol, int tid,
                                              float* dst, size_t ldT, int m0) {
  __syncthreads();
#pragma unroll
  for (int r = 0; r < 4; ++r) t[lcol * 33 + lrow + r] = v[r];
  __syncthreads();
  int i = tid >> 3, j = (tid & 7) * 4;
  float4 o = make_float4(t[i * 33 + j], t[i * 33 + j + 1],
                         t[i * 33 + j + 2], t[i * 33 + j + 3]);
  *(float4*)&dst[(size_t)i * ldT + m0 + j] = o;
}

// ---------------------------------------------------------------------------
// prep: LN + cvt(Wi) + cvt(Wx B/C rows) + cvt(Wo) + Weff tiles (R9/R10).
// ---------------------------------------------------------------------------
__global__ __launch_bounds__(256) void prep(
    const float* __restrict__ x, const float* __restrict__ lnw,
    const float* __restrict__ lnb, short* __restrict__ h,
    const float* __restrict__ wi, short* __restrict__ wib,
    const float* __restrict__ wx, const float* __restrict__ wdt,
    short* __restrict__ wcomb, const float* __restrict__ wo,
    short* __restrict__ wob) {
  __shared__ float ls[4], ls2[4];
  int b = blockIdx.x;
  int tid = threadIdx.x, lane = tid & 63, w = tid >> 6;
  if (b < J_LN) {
    int l = b;
    const float* xr = x + l * DM;
    float s = 0.f, s2 = 0.f;
    for (int i = tid; i < DM; i += 256) { float t = xr[i]; s += t; s2 += t * t; }
#pragma unroll
    for (int off = 32; off; off >>= 1) { s += __shfl_xor(s, off); s2 += __shfl_xor(s2, off); }
    if (lane == 0) { ls[w] = s; ls2[w] = s2; }
    __syncthreads();
    s = ls[0] + ls[1] + ls[2] + ls[3];
    s2 = ls2[0] + ls2[1] + ls2[2] + ls2[3];
    float mean = s * (1.f / DM);
    float var = s2 * (1.f / DM) - mean * mean;
    float rstd = rsqrtf(var + 1e-5f);
    for (int i = tid; i < DM; i += 256)
      h[l * DM + i] = f2bf((xr[i] - mean) * rstd * lnw[i] + lnb[i]);
    return;
  }
  b -= J_LN;
  if (b < J_WI) { cvt_blk(wi, wib, b); return; }
  b -= J_WI;
  if (b < J_WBC) { cvt_blk(wx + DR * DI, wcomb, b); return; }
  b -= J_WBC;
  if (b < J_WO) { cvt_blk(wo, wob, b); return; }
  b -= J_WO;
  {
    int tm = b / (DI / 64), tn = b % (DI / 64);
    int qi = w & 1, qj = w >> 1;
    int m0 = tm * 64 + qi * 32, n0 = tn * 64 + qj * 32;
    int fr = lane & 15, koff = (lane >> 4) * 8;
    const float* pA0 = wdt + (size_t)(m0 + fr) * DR;
    const float* pA1 = pA0 + (size_t)16 * DR;
    float4v a00 = (float4v){0.f,0.f,0.f,0.f}, a01 = a00, a10 = a00, a11 = a00;
#pragma unroll
    for (int k0 = 0; k0 < 64; k0 += 32) {
      bool valid = (k0 + koff) < DR;
      int off = valid ? k0 + koff : 0;
      short8 fa0 = cvt8f(pA0 + off, valid);
      short8 fa1 = cvt8f(pA1 + off, valid);
      short8 fb0, fb1;
#pragma unroll
      for (int j = 0; j < 8; ++j) {
        int r = k0 + koff + j;
        fb0[j] = valid ? f2bf(wx[(size_t)r * DI + n0 + fr]) : (short)0;
        fb1[j] = valid ? f2bf(wx[(size_t)r * DI + n0 + 16 + fr]) : (short)0;
      }
      a00 = __builtin_amdgcn_mfma_f32_16x16x32_bf16(fa0, fb0, a00, 0, 0, 0);
      a01 = __builtin_amdgcn_mfma_f32_16x16x32_bf16(fa0, fb1, a01, 0, 0, 0);
      a10 = __builtin_amdgcn_mfma_f32_16x16x32_bf16(fa1, fb0, a10, 0, 0, 0);
      a11 = __builtin_amdgcn_mfma_f32_16x16x32_bf16(fa1, fb1, a11, 0, 0, 0);
    }
    int rb = (lane >> 4) * 4, cb = lane & 15;
#pragma unroll
    for (int r = 0; r < 4; ++r) {
      wcomb[(size_t)(NBC + m0 + rb + r) * DI + n0 + cb]      = f2bf(a00[r]);
      wcomb[(size_t)(NBC + m0 + rb + r) * DI + n0 + 16 + cb] = f2bf(a01[r]);
      wcomb[(size_t)(NBC + m0 + 16 + rb + r) * DI + n0 + cb]      = f2bf(a10[r]);
      wcomb[(size_t)(NBC + m0 + 16 + rb + r) * DI + n0 + 16 + cb] = f2bf(a11[r]);
    }
  }
}

// ---------------------------------------------------------------------------
// in_proj: cols<DI -> xz_in[l][col]; cols>=DI -> zt[d][l] transposed. (R10)
// ---------------------------------------------------------------------------
__global__ __launch_bounds__(256) void k_inproj(const short* __restrict__ h,
                                                const short* __restrict__ wi,
                                                float* __restrict__ xz_in,
                                                float* __restrict__ zt) {
  __shared__ float4v red[16 * 64];
  int tid = threadIdx.x, lane = tid & 63, w = tid >> 6;
  float4v v = gemm32_core(h, DM, wi, DM, DM, blockIdx.x, blockIdx.y, lane, w, red);
  int lrow = ((w & 1) << 4) + ((lane >> 4) << 2);
  int lcol = ((w >> 1) << 4) + (lane & 15);
  int m0 = blockIdx.y * 32, n0 = blockIdx.x * 32;
  if (n0 < DI) {
#pragma unroll
    for (int r = 0; r < 4; ++r)
      xz_in[(size_t)(m0 + lrow + r) * DI + n0 + lcol] = v[r];
  } else {
    trans_store32((float*)red, v, lrow, lcol, tid,
                  zt + (size_t)(n0 - DI) * L_SEQ, L_SEQ, m0);
  }
}

// ---------------------------------------------------------------------------
// conv + SiLU (R10): xc_bf[l][d] + xct[d][l].
// ---------------------------------------------------------------------------
__global__ __launch_bounds__(256) void conv_silu_kernel(const float* __restrict__ xz_in,
                                                        const float* __restrict__ cw,
                                                        const float* __restrict__ cb,
                                                        short* __restrict__ xc_bf,
                                                        float* __restrict__ xct) {
  __shared__ float t2[64 * 34];
  int tid = threadIdx.x;
  int dloc = tid & 63, lseg = tid >> 6;
  int d0 = blockIdx.x * 64, l0 = blockIdx.y * 32;
  int d = d0 + dloc;
  int lb = l0 + lseg * 8;
  float xin[11];
#pragma unroll
  for (int i = 0; i < 11; ++i) {
    int l = lb - 3 + i;
    xin[i] = (l >= 0) ? xz_in[(size_t)l * DI + d] : 0.f;
  }
  float w0 = cw[d * 4 + 0], w1 = cw[d * 4 + 1];
  float w2 = cw[d * 4 + 2], w3 = cw[d * 4 + 3];
  float bias = cb[d];
#pragma unroll
  for (int j = 0; j < 8; ++j) {
    float acc = bias;
    acc = fmaf(w0, xin[j], acc);
    acc = fmaf(w1, xin[j + 1], acc);
    acc = fmaf(w2, xin[j + 2], acc);
    acc = fmaf(w3, xin[j + 3], acc);
    float sig = 1.f / (1.f + __expf(-acc));
    float v = acc * sig;
    xc_bf[(size_t)(lb + j) * DI + d] = f2bf(v);
    t2[dloc * 34 + lseg * 8 + j] = v;
  }
  __syncthreads();
  int row = tid >> 2, j4 = (tid & 3) * 8;
  const float* src = &t2[row * 34 + j4];
  float2 o0 = *(const float2*)(src + 0);
  float2 o1 = *(const float2*)(src + 2);
  float2 o2 = *(const float2*)(src + 4);
  float2 o3 = *(const float2*)(src + 6);
  float* dst = &xct[(size_t)(d0 + row) * L_SEQ + l0 + j4];
  *(float2*)(dst + 0) = o0; *(float2*)(dst + 2) = o1;
  *(float2*)(dst + 4) = o2; *(float2*)(dst + 6) = o3;
}

// ---------------------------------------------------------------------------
// proj2 (R12): B/C INTERLEAVED [l][2n]=B_n, [l][2n+1]=C_n; dt transposed.
// ---------------------------------------------------------------------------
__global__ __launch_bounds__(256) void k_proj2(const short* __restrict__ xc,
                                               const short* __restrict__ wcomb,
                                               float* __restrict__ xdblBC,
                                               float* __restrict__ dtt,
                                               const float* __restrict__ bias) {
  __shared__ float4v red[16 * 64];
  int tid = threadIdx.x, lane = tid & 63, w = tid >> 6;
  float4v v = gemm32_core(xc, DI, wcomb, DI, DI, blockIdx.x, blockIdx.y,
                          lane, w, red);
  int lrow = ((w & 1) << 4) + ((lane >> 4) << 2);
  int lcol = ((w >> 1) << 4) + (lane & 15);
  int m0 = blockIdx.y * 32, n0 = blockIdx.x * 32;
  if (n0 < NBC) {
    int idx = n0 + lcol;
    int pos = (idx < DS) ? (idx << 1) : (((idx - DS) << 1) | 1);
#pragma unroll
    for (int r = 0; r < 4; ++r)
      xdblBC[(size_t)(m0 + lrow + r) * NBC + pos] = v[r];
  } else {
    float bi = bias[n0 - NBC + lcol];
#pragma unroll
    for (int r = 0; r < 4; ++r) {
      float t = v[r] + bi;
      v[r] = (t > 20.f) ? t : log1pf(__expf(t));
    }
    trans_store32((float*)red, v, lrow, lcol, tid,
                  dtt + (size_t)(n0 - NBC) * L_SEQ, L_SEQ, m0);
  }
}

// ---------------------------------------------------------------------------
// Fused selective scan, occupancy-optimized:
// Block = 512 thr = 8 waves = ONE channel x 8 chunks of 64 steps.
// Grid = DI = 1536. LDS ~35.8 KB -> 4 blocks/CU = 32 waves/CU (100%).
// __expf (R12's exp2f regression reverted); dtx precompute; interleaved
// float2 B/C; R11-proven float2/stride-66 reduce. After the route, lane L
// of wave c holds y for l = c*64+L = tid -> direct store, no ys buffer.
// ---------------------------------------------------------------------------
__global__ __launch_bounds__(512) void scan_fused(const float* __restrict__ dtt,
                                                  const float* __restrict__ xct,
                                                  const float* __restrict__ xdblBC,
                                                  const float* __restrict__ A_log,
                                                  const float* __restrict__ Dv,
                                                  const float* __restrict__ zt,
                                                  short* __restrict__ y) {
  __shared__ float Pb[8][16][66];     // 33.8 KB, wave-private slices
  __shared__ float sendL[8][64];      // 2 KB (chunks 0..6 used)
  __shared__ float dtsL[8];
  int tid = threadIdx.x;
  int lane = tid & 63;
  int c = tid >> 6;            // wave = chunk 0..7
  int d = blockIdx.x;
  float A = -__expf(A_log[(size_t)d * DS + lane]);
  int l0 = c * TCF;
  float dtv = dtt[(size_t)d * L_SEQ + l0 + lane];
  float xv  = xct[(size_t)d * L_SEQ + l0 + lane];
  float zv  = zt[(size_t)d * L_SEQ + l0 + lane];
  float dtxv = dtv * xv;
  const float* pB = xdblBC + (size_t)l0 * NBC + 2 * lane;

  // ---- Phase A (chunk 7's end state never consumed -> skip) ----
  if (c < 7) {
    float s = 0.f;
#pragma unroll 8
    for (int t = 0; t < TCF; ++t) {
      float dt_c  = lane_read(dtv, t);
      float dtx_c = lane_read(dtxv, t);
      float2 bc = *(const float2*)&pB[(size_t)t * NBC];
      s = fmaf(__expf(dt_c * A), s, dtx_c * bc.x);
    }
    float dsum = dtv;
    dsum = bp_add(dsum, (lane ^ 1) << 2);  dsum = bp_add(dsum, (lane ^ 2) << 2);
    dsum = bp_add(dsum, (lane ^ 4) << 2);  dsum = bp_add(dsum, (lane ^ 8) << 2);
    dsum = bp_add(dsum, (lane ^ 16) << 2); dsum = bp_add(dsum, (lane ^ 32) << 2);
    sendL[c][lane] = s;
    if (lane == 0) dtsL[c] = dsum;
  }
  __syncthreads();

  // ---- In-block prefix: init state for this chunk (<=7 iterations) ----
  float s = 0.f;
  for (int cc = 0; cc < c; ++cc) {
    float P = __expf(A * dtsL[cc]);
    s = fmaf(P, s, sendL[cc][lane]);
  }

  // ---- Phase C: scan with y (R11-proven LDS-batched n-reduction) ----
  float yv = 0.f;
#pragma unroll
  for (int sb = 0; sb < 4; ++sb) {
    float P[16];
#pragma unroll
    for (int j = 0; j < 16; ++j) {
      int t = sb * 16 + j;
      float dt_c  = lane_read(dtv, t);
      float dtx_c = lane_read(dtxv, t);
      float2 bc = *(const float2*)&pB[(size_t)t * NBC];
      s = fmaf(__expf(dt_c * A), s, dtx_c * bc.x);
      P[j] = s * bc.y;
    }
#pragma unroll
    for (int j = 0; j < 16; ++j) Pb[c][j][lane] = P[j];
    int t4 = lane >> 2, q = lane & 3;
    const float* row = &Pb[c][t4][q * 16];
    float part = 0.f;
#pragma unroll
    for (int k = 0; k < 8; ++k) {
      float2 v2 = *(const float2*)(row + 2 * k);
      part += v2.x + v2.y;
    }
    part = bp_add(part, (lane ^ 1) << 2);
    part = bp_add(part, (lane ^ 2) << 2);
    float got = __int_as_float(
        __builtin_amdgcn_ds_bpermute((lane & 15) << 4, __float_as_int(part)));
    yv = ((lane >> 4) == sb) ? got : yv;
  }

  // ---- Epilogue: lane L of wave c holds y for l = tid -> direct store ----
  float Dd = Dv[d];
  float sig = 1.f / (1.f + __expf(-zv));
  y[(size_t)tid * DI + d] = f2bf((yv + xv * Dd) * (zv * sig));
}

// ---------------------------------------------------------------------------
// out_proj + residual (R10).
// ---------------------------------------------------------------------------
__global__ __launch_bounds__(256) void k_outproj(const short* __restrict__ y,
                                                 const short* __restrict__ wo,
                                                 const float* __restrict__ x,
                                                 float* __restrict__ out) {
  __shared__ float4v red[16 * 64];
  int tid = threadIdx.x, lane = tid & 63, w = tid >> 6;
  float4v v = gemm32_core(y, DI, wo, DI, DI, blockIdx.x, blockIdx.y, lane, w, red);
  int lrow = ((w & 1) << 4) + ((lane >> 4) << 2);
  int lcol = ((w >> 1) << 4) + (lane & 15);
  int row = blockIdx.y * 32 + lrow, col = blockIdx.x * 32 + lcol;
#pragma unroll
  for (int r = 0; r < 4; ++r)
    out[(size_t)(row + r) * DM + col] = v[r] + x[(size_t)(row + r) * DM + col];
}

// ---------------------------------------------------------------------------
// Launcher (6 dispatches)
// ---------------------------------------------------------------------------
extern "C" void kernel_launch(void* const* d_in, const int* in_sizes, int n_in,
                              void* d_out, int out_size, void* d_ws, size_t ws_size,
                              hipStream_t stream) {
  const float* x         = (const float*)d_in[0];
  const float* ln_w      = (const float*)d_in[1];
  const float* ln_b      = (const float*)d_in[2];
  const float* in_proj_w = (const float*)d_in[3];
  const float* conv_w    = (const float*)d_in[4];
  const float* conv_b    = (const float*)d_in[5];
  const float* x_proj_w  = (const float*)d_in[6];
  const float* dt_proj_w = (const float*)d_in[7];
  const float* dt_proj_b = (const float*)d_in[8];
  const float* A_log     = (const float*)d_in[9];
  const float* Dv        = (const float*)d_in[10];
  const float* out_proj_w= (const float*)d_in[11];
  float* out = (float*)d_out;

  float* ws = (float*)d_ws;
  // f32 region
  float* xz_in  = ws;                      // 512*1536 = 786432
  float* zt     = xz_in + 786432;          // 1536*512 (transposed z)
  float* xct    = zt + 786432;             // 1536*512 (transposed conv)
  float* dtt    = xct + 786432;            // 1536*512 (transposed dt)
  float* xdblBC = dtt + 786432;            // 512*128 = 65536 (interleaved B/C)
  float* fend   = xdblBC + 65536;
  // bf16 region
  short* h_bf   = (short*)fend;            // 393216
  short* wi_bf  = h_bf + 393216;           // 2359296
  short* wo_bf  = wi_bf + 2359296;         // 1179648
  short* wcomb  = wo_bf + 1179648;         // 1664*1536 = 2555904
  short* xc_bf  = wcomb + 2555904;         // 786432
  short* y_bf   = xc_bf + 786432;          // 786432

  // 1. prep: LN + weight cvts + Weff build
  prep<<<PREP_GRID, 256, 0, stream>>>(x, ln_w, ln_b, h_bf, in_proj_w, wi_bf,
                                      x_proj_w, dt_proj_w, wcomb,
                                      out_proj_w, wo_bf);

  // 2. in_proj: x_in row-major + z transposed
  k_inproj<<<dim3(2 * DI / 32, L_SEQ / 32), 256, 0, stream>>>(h_bf, wi_bf,
                                                              xz_in, zt);

  // 3. conv + SiLU
  conv_silu_kernel<<<dim3(DI / 64, L_SEQ / 32), 256, 0, stream>>>(
      xz_in, conv_w, conv_b, xc_bf, xct);

  // 4. proj2: [B/C | dt] = xconv . Wcomb^T (B/C interleaved)
  k_proj2<<<dim3(NP2 / 32, L_SEQ / 32), 256, 0, stream>>>(
      xc_bf, wcomb, xdblBC, dtt, dt_proj_b);

  // 5. fused selective scan (1 channel x 8 chunks, 32 waves/CU)
  scan_fused<<<DI, 512, 0, stream>>>(dtt, xct, xdblBC, A_log, Dv, zt, y_bf);

  // 6. out_proj + residual
  k_outproj<<<dim3(DM / 32, L_SEQ / 32), 256, 0, stream>>>(y_bf, wo_bf, x, out);
}

// Round 14
// 184.983 us; speedup vs baseline: 1.0870x; 1.0870x over previous
//
#include <hip/hip_runtime.h>
#include <hip/hip_bf16.h>
#include <math.h>

#define L_SEQ 512
#define DM 768
#define DI 1536
#define DS 64
#define DC 4
#define DR 48
#define NBC 128          // B/C output columns (2*DS)
#define NP2 (NBC + DI)   // 1664: proj2 output width (B/C | dt)
#define NC 8             // time chunks
#define TC 64            // steps per chunk

typedef __attribute__((ext_vector_type(8))) short short8;
typedef __attribute__((ext_vector_type(4))) float float4v;

// prep job partition (1024-elem cvt jobs + LN rows + Weff tiles)
#define J_LN 512
#define J_WI (2 * DI * DM / 1024)   // 2304
#define J_WBC (NBC * DI / 1024)     // 192
#define J_WO (DM * DI / 1024)       // 1152
#define J_WEFF ((DI / 64) * (DI / 64))  // 576
#define PREP_GRID (J_LN + J_WI + J_WBC + J_WO + J_WEFF)  // 4736

// ---------------------------------------------------------------------------
// helpers
// ---------------------------------------------------------------------------
__device__ __forceinline__ float bp_add(float p, int addr) {
  return p + __int_as_float(__builtin_amdgcn_ds_bpermute(addr, __float_as_int(p)));
}
__device__ __forceinline__ float lane_read(float v, int t) {
  return __int_as_float(__builtin_amdgcn_readlane(__float_as_int(v), t));
}
__device__ __forceinline__ short f2bf(float v) {
  __hip_bfloat16 h = __float2bfloat16(v);
  return *reinterpret_cast<short*>(&h);
}
__device__ __forceinline__ short8 cvt8f(const float* p, bool valid) {
  float4 u = *(const float4*)(p);
  float4 v = *(const float4*)(p + 4);
  short8 r;
  r[0] = f2bf(u.x); r[1] = f2bf(u.y); r[2] = f2bf(u.z); r[3] = f2bf(u.w);
  r[4] = f2bf(v.x); r[5] = f2bf(v.y); r[6] = f2bf(v.z); r[7] = f2bf(v.w);
  if (!valid) r = (short8)0;
  return r;
}
__device__ __forceinline__ void cvt_blk(const float* __restrict__ s,
                                        short* __restrict__ d, int b) {
  int i = b * 1024 + threadIdx.x * 4;
  float4 v = *(const float4*)(s + i);
  short4 o; o.x = f2bf(v.x); o.y = f2bf(v.y); o.z = f2bf(v.z); o.w = f2bf(v.w);
  *(short4*)(d + i) = o;
}

// ---------------------------------------------------------------------------
// 32x32-tile GEMM core with 4-wave intra-block K-split + LDS reduce
// (verified R9/R10). Caller coords: lrow=(w&1)*16+(lane>>4)*4,
// lcol=(w>>1)*16+(lane&15).
// ---------------------------------------------------------------------------
__device__ __forceinline__ float4v gemm32_core(
    const short* __restrict__ A, int lda, const short* __restrict__ B, int ldb,
    int K, int bx, int by, int lane, int w, float4v* red) {
  int ks = K >> 2;
  int kbeg = w * ks;
  int fr = lane & 15, koff = (lane >> 4) * 8;
  int m0 = by * 32, n0 = bx * 32;
  const short* pA0 = A + (size_t)(m0 + fr) * lda + koff + kbeg;
  const short* pA1 = pA0 + (size_t)16 * lda;
  const short* pB0 = B + (size_t)(n0 + fr) * ldb + koff + kbeg;
  const short* pB1 = pB0 + (size_t)16 * ldb;
  float4v acc00 = (float4v){0.f,0.f,0.f,0.f}, acc01 = acc00;
  float4v acc10 = acc00, acc11 = acc00;
  short8 a0A = *(const short8*)(pA0);      short8 a1A = *(const short8*)(pA1);
  short8 b0A = *(const short8*)(pB0);      short8 b1A = *(const short8*)(pB1);
  short8 a0B = *(const short8*)(pA0 + 32); short8 a1B = *(const short8*)(pA1 + 32);
  short8 b0B = *(const short8*)(pB0 + 32); short8 b1B = *(const short8*)(pB1 + 32);
  for (int k0 = 0; k0 < ks; k0 += 64) {
    short8 ca0 = a0A, ca1 = a1A, cb0 = b0A, cb1 = b1A;
    short8 da0 = a0B, da1 = a1B, db0 = b0B, db1 = b1B;
    int nA = k0 + 64; if (nA >= ks) nA = 0;
    int nB = k0 + 96; if (nB >= ks) nB = 32;
    a0A = *(const short8*)(pA0 + nA); a1A = *(const short8*)(pA1 + nA);
    b0A = *(const short8*)(pB0 + nA); b1A = *(const short8*)(pB1 + nA);
    a0B = *(const short8*)(pA0 + nB); a1B = *(const short8*)(pA1 + nB);
    b0B = *(const short8*)(pB0 + nB); b1B = *(const short8*)(pB1 + nB);
    acc00 = __builtin_amdgcn_mfma_f32_16x16x32_bf16(ca0, cb0, acc00, 0, 0, 0);
    acc01 = __builtin_amdgcn_mfma_f32_16x16x32_bf16(ca0, cb1, acc01, 0, 0, 0);
    acc10 = __builtin_amdgcn_mfma_f32_16x16x32_bf16(ca1, cb0, acc10, 0, 0, 0);
    acc11 = __builtin_amdgcn_mfma_f32_16x16x32_bf16(ca1, cb1, acc11, 0, 0, 0);
    acc00 = __builtin_amdgcn_mfma_f32_16x16x32_bf16(da0, db0, acc00, 0, 0, 0);
    acc01 = __builtin_amdgcn_mfma_f32_16x16x32_bf16(da0, db1, acc01, 0, 0, 0);
    acc10 = __builtin_amdgcn_mfma_f32_16x16x32_bf16(da1, db0, acc10, 0, 0, 0);
    acc11 = __builtin_amdgcn_mfma_f32_16x16x32_bf16(da1, db1, acc11, 0, 0, 0);
  }
  red[(w * 4 + 0) * 64 + lane] = acc00;
  red[(w * 4 + 1) * 64 + lane] = acc01;
  red[(w * 4 + 2) * 64 + lane] = acc10;
  red[(w * 4 + 3) * 64 + lane] = acc11;
  __syncthreads();
  float4v v = red[(0 * 4 + w) * 64 + lane];
  v = v + red[(1 * 4 + w) * 64 + lane];
  v = v + red[(2 * 4 + w) * 64 + lane];
  v = v + red[(3 * 4 + w) * 64 + lane];
  return v;
}

// ---------------------------------------------------------------------------
// 32x32 transposed store (verified R10).
// ---------------------------------------------------------------------------
__device__ __forceinline__ void trans_store32(float* t, float4v v,
                                              int lrow, int lcol, int tid,
                                              float* dst, size_t ldT, int m0) {
  __syncthreads();   // all waves done reading red
#pragma unroll
  for (int r = 0; r < 4; ++r) t[lcol * 33 + lrow + r] = v[r];
  __syncthreads();
  int i = tid >> 3, j = (tid & 7) * 4;
  float4 o = make_float4(t[i * 33 + j], t[i * 33 + j + 1],
                         t[i * 33 + j + 2], t[i * 33 + j + 3]);
  *(float4*)&dst[(size_t)i * ldT + m0 + j] = o;
}

// ---------------------------------------------------------------------------
// prep: LN + cvt(Wi) + cvt(Wx B/C rows) + cvt(Wo) + Weff tiles.
// R14 change: Weff build stages wx's 64-col slice in LDS (coalesced row
// loads, bf16, stride 56 = 16B-aligned b128 fragment reads) instead of
// 6KB-strided column gathers.
// ---------------------------------------------------------------------------
__global__ __launch_bounds__(256) void prep(
    const float* __restrict__ x, const float* __restrict__ lnw,
    const float* __restrict__ lnb, short* __restrict__ h,
    const float* __restrict__ wi, short* __restrict__ wib,
    const float* __restrict__ wx, const float* __restrict__ wdt,
    short* __restrict__ wcomb, const float* __restrict__ wo,
    short* __restrict__ wob) {
  __shared__ float ls[4], ls2[4];
  __shared__ short wxs[64 * 56];   // 7 KB: wx slice, [col][r], stride 56
  int b = blockIdx.x;
  int tid = threadIdx.x, lane = tid & 63, w = tid >> 6;
  if (b < J_LN) {
    int l = b;
    const float* xr = x + l * DM;
    float s = 0.f, s2 = 0.f;
    for (int i = tid; i < DM; i += 256) { float t = xr[i]; s += t; s2 += t * t; }
#pragma unroll
    for (int off = 32; off; off >>= 1) { s += __shfl_xor(s, off); s2 += __shfl_xor(s2, off); }
    if (lane == 0) { ls[w] = s; ls2[w] = s2; }
    __syncthreads();
    s = ls[0] + ls[1] + ls[2] + ls[3];
    s2 = ls2[0] + ls2[1] + ls2[2] + ls2[3];
    float mean = s * (1.f / DM);
    float var = s2 * (1.f / DM) - mean * mean;
    float rstd = rsqrtf(var + 1e-5f);
    for (int i = tid; i < DM; i += 256)
      h[l * DM + i] = f2bf((xr[i] - mean) * rstd * lnw[i] + lnb[i]);
    return;
  }
  b -= J_LN;
  if (b < J_WI) { cvt_blk(wi, wib, b); return; }
  b -= J_WI;
  if (b < J_WBC) { cvt_blk(wx + DR * DI, wcomb, b); return; }
  b -= J_WBC;
  if (b < J_WO) { cvt_blk(wo, wob, b); return; }
  b -= J_WO;
  {
    int tm = b / (DI / 64), tn = b % (DI / 64);
    // stage wx[0:48][tn*64 .. +64) -> wxs[c][r] (bf16, transposed, coalesced)
#pragma unroll
    for (int rr = 0; rr < 12; ++rr) {
      int r = rr * 4 + (tid >> 6);
      int cc = tid & 63;
      wxs[cc * 56 + r] = f2bf(wx[(size_t)r * DI + tn * 64 + cc]);
    }
    __syncthreads();
    int qi = w & 1, qj = w >> 1;
    int m0 = tm * 64 + qi * 32, n0 = tn * 64 + qj * 32;
    int nl = qj * 32;
    int fr = lane & 15, koff = (lane >> 4) * 8;
    const float* pA0 = wdt + (size_t)(m0 + fr) * DR;
    const float* pA1 = pA0 + (size_t)16 * DR;
    float4v a00 = (float4v){0.f,0.f,0.f,0.f}, a01 = a00, a10 = a00, a11 = a00;
#pragma unroll
    for (int k0 = 0; k0 < 64; k0 += 32) {
      bool valid = (k0 + koff) < DR;
      int off = valid ? k0 + koff : 0;
      short8 fa0 = cvt8f(pA0 + off, valid);
      short8 fa1 = cvt8f(pA1 + off, valid);
      short8 fb0 = *(const short8*)&wxs[(nl + fr) * 56 + off];
      short8 fb1 = *(const short8*)&wxs[(nl + 16 + fr) * 56 + off];
      if (!valid) { fb0 = (short8)0; fb1 = (short8)0; }
      a00 = __builtin_amdgcn_mfma_f32_16x16x32_bf16(fa0, fb0, a00, 0, 0, 0);
      a01 = __builtin_amdgcn_mfma_f32_16x16x32_bf16(fa0, fb1, a01, 0, 0, 0);
      a10 = __builtin_amdgcn_mfma_f32_16x16x32_bf16(fa1, fb0, a10, 0, 0, 0);
      a11 = __builtin_amdgcn_mfma_f32_16x16x32_bf16(fa1, fb1, a11, 0, 0, 0);
    }
    int rb = (lane >> 4) * 4, cb = lane & 15;
#pragma unroll
    for (int r = 0; r < 4; ++r) {
      wcomb[(size_t)(NBC + m0 + rb + r) * DI + n0 + cb]      = f2bf(a00[r]);
      wcomb[(size_t)(NBC + m0 + rb + r) * DI + n0 + 16 + cb] = f2bf(a01[r]);
      wcomb[(size_t)(NBC + m0 + 16 + rb + r) * DI + n0 + cb]      = f2bf(a10[r]);
      wcomb[(size_t)(NBC + m0 + 16 + rb + r) * DI + n0 + 16 + cb] = f2bf(a11[r]);
    }
  }
}

// ---------------------------------------------------------------------------
// in_proj: cols<DI -> xz_in[l][col]; cols>=DI -> zt[d][l] transposed. (R10)
// ---------------------------------------------------------------------------
__global__ __launch_bounds__(256) void k_inproj(const short* __restrict__ h,
                                                const short* __restrict__ wi,
                                                float* __restrict__ xz_in,
                                                float* __restrict__ zt) {
  __shared__ float4v red[16 * 64];
  int tid = threadIdx.x, lane = tid & 63, w = tid >> 6;
  float4v v = gemm32_core(h, DM, wi, DM, DM, blockIdx.x, blockIdx.y, lane, w, red);
  int lrow = ((w & 1) << 4) + ((lane >> 4) << 2);
  int lcol = ((w >> 1) << 4) + (lane & 15);
  int m0 = blockIdx.y * 32, n0 = blockIdx.x * 32;
  if (n0 < DI) {
#pragma unroll
    for (int r = 0; r < 4; ++r)
      xz_in[(size_t)(m0 + lrow + r) * DI + n0 + lcol] = v[r];
  } else {
    trans_store32((float*)red, v, lrow, lcol, tid,
                  zt + (size_t)(n0 - DI) * L_SEQ, L_SEQ, m0);
  }
}

// ---------------------------------------------------------------------------
// conv + SiLU (R10): xc_bf[l][d] + xct[d][l].
// ---------------------------------------------------------------------------
__global__ __launch_bounds__(256) void conv_silu_kernel(const float* __restrict__ xz_in,
                                                        const float* __restrict__ cw,
                                                        const float* __restrict__ cb,
                                                        short* __restrict__ xc_bf,
                                                        float* __restrict__ xct) {
  __shared__ float t2[64 * 34];
  int tid = threadIdx.x;
  int dloc = tid & 63, lseg = tid >> 6;
  int d0 = blockIdx.x * 64, l0 = blockIdx.y * 32;
  int d = d0 + dloc;
  int lb = l0 + lseg * 8;
  float xin[11];
#pragma unroll
  for (int i = 0; i < 11; ++i) {
    int l = lb - 3 + i;
    xin[i] = (l >= 0) ? xz_in[(size_t)l * DI + d] : 0.f;
  }
  float w0 = cw[d * 4 + 0], w1 = cw[d * 4 + 1];
  float w2 = cw[d * 4 + 2], w3 = cw[d * 4 + 3];
  float bias = cb[d];
#pragma unroll
  for (int j = 0; j < 8; ++j) {
    float acc = bias;
    acc = fmaf(w0, xin[j], acc);
    acc = fmaf(w1, xin[j + 1], acc);
    acc = fmaf(w2, xin[j + 2], acc);
    acc = fmaf(w3, xin[j + 3], acc);
    float sig = 1.f / (1.f + __expf(-acc));
    float v = acc * sig;
    xc_bf[(size_t)(lb + j) * DI + d] = f2bf(v);
    t2[dloc * 34 + lseg * 8 + j] = v;
  }
  __syncthreads();
  int row = tid >> 2, j4 = (tid & 3) * 8;
  const float* src = &t2[row * 34 + j4];
  float2 o0 = *(const float2*)(src + 0);
  float2 o1 = *(const float2*)(src + 2);
  float2 o2 = *(const float2*)(src + 4);
  float2 o3 = *(const float2*)(src + 6);
  float* dst = &xct[(size_t)(d0 + row) * L_SEQ + l0 + j4];
  *(float2*)(dst + 0) = o0; *(float2*)(dst + 2) = o1;
  *(float2*)(dst + 4) = o2; *(float2*)(dst + 6) = o3;
}

// ---------------------------------------------------------------------------
// proj2 (R10): B/C row-major (cols 0..63 = B, 64..127 = C); dt transposed.
// ---------------------------------------------------------------------------
__global__ __launch_bounds__(256) void k_proj2(const short* __restrict__ xc,
                                               const short* __restrict__ wcomb,
                                               float* __restrict__ xdblBC,
                                               float* __restrict__ dtt,
                                               const float* __restrict__ bias) {
  __shared__ float4v red[16 * 64];
  int tid = threadIdx.x, lane = tid & 63, w = tid >> 6;
  float4v v = gemm32_core(xc, DI, wcomb, DI, DI, blockIdx.x, blockIdx.y,
                          lane, w, red);
  int lrow = ((w & 1) << 4) + ((lane >> 4) << 2);
  int lcol = ((w >> 1) << 4) + (lane & 15);
  int m0 = blockIdx.y * 32, n0 = blockIdx.x * 32;
  if (n0 < NBC) {
#pragma unroll
    for (int r = 0; r < 4; ++r)
      xdblBC[(size_t)(m0 + lrow + r) * NBC + n0 + lcol] = v[r];
  } else {
    float bi = bias[n0 - NBC + lcol];
#pragma unroll
    for (int r = 0; r < 4; ++r) {
      float t = v[r] + bi;
      v[r] = (t > 20.f) ? t : log1pf(__expf(t));
    }
    trans_store32((float*)red, v, lrow, lcol, tid,
                  dtt + (size_t)(n0 - NBC) * L_SEQ, L_SEQ, m0);
  }
}

// ---------------------------------------------------------------------------
// Scan pass 1 (chunks 0..NC-2): coalesced dtt/xct preloads; dtx precompute.
// ---------------------------------------------------------------------------
__global__ __launch_bounds__(256) void scan_p1(const float* __restrict__ dtt,
                                               const float* __restrict__ xct,
                                               const float* __restrict__ xdblBC,
                                               const float* __restrict__ A_log,
                                               float* __restrict__ send,
                                               float* __restrict__ dts) {
  int lane = threadIdx.x & 63;
  int wid = threadIdx.x >> 6;
  int pair = blockIdx.x * 4 + wid;
  int c = __builtin_amdgcn_readfirstlane(pair / DI);
  int d = __builtin_amdgcn_readfirstlane(pair - (pair / DI) * DI);
  float A = -__expf(A_log[(size_t)d * DS + lane]);
  int l0 = c * TC;
  float dtv = dtt[(size_t)d * L_SEQ + l0 + lane];
  float xv  = xct[(size_t)d * L_SEQ + l0 + lane];
  float dtxv = dtv * xv;
  const float* pB = xdblBC + (size_t)l0 * NBC + lane;
  float s = 0.f;
#pragma unroll 8
  for (int t = 0; t < TC; ++t) {
    float dt_c  = lane_read(dtv, t);
    float dtx_c = lane_read(dtxv, t);
    float B_c   = pB[(size_t)t * NBC];
    float dA = __expf(dt_c * A);
    s = fmaf(dA, s, dtx_c * B_c);
  }
  float dsum = dtv;
  dsum = bp_add(dsum, (lane ^ 1) << 2);  dsum = bp_add(dsum, (lane ^ 2) << 2);
  dsum = bp_add(dsum, (lane ^ 4) << 2);  dsum = bp_add(dsum, (lane ^ 8) << 2);
  dsum = bp_add(dsum, (lane ^ 16) << 2); dsum = bp_add(dsum, (lane ^ 32) << 2);
  send[((size_t)c * DI + d) * DS + lane] = s;
  if (lane == 0) dts[c * DI + d] = dsum;
}

// ---------------------------------------------------------------------------
// Scan pass 3: inline chunk-prefix; coalesced preloads; dtx precompute;
// LDS-batched n-reduction; y stored via LDS short4 rows.
// ---------------------------------------------------------------------------
__global__ __launch_bounds__(256) void scan_p3(const float* __restrict__ dtt,
                                               const float* __restrict__ xct,
                                               const float* __restrict__ xdblBC,
                                               const float* __restrict__ A_log,
                                               const float* __restrict__ Dv,
                                               const float* __restrict__ zt,
                                               const float* __restrict__ send,
                                               const float* __restrict__ dts,
                                               short* __restrict__ y) {
  __shared__ float Pb[4][16][66];
  __shared__ float ys[64][5];
  int tid = threadIdx.x;
  int lane = tid & 63;
  int wid = tid >> 6;
  int pair = blockIdx.x * 4 + wid;
  int c = __builtin_amdgcn_readfirstlane(pair / DI);
  int d = __builtin_amdgcn_readfirstlane(pair - (pair / DI) * DI);
  float A = -__expf(A_log[(size_t)d * DS + lane]);
  float Dd = Dv[d];
  int l0 = c * TC;
  float dtv = dtt[(size_t)d * L_SEQ + l0 + lane];
  float xv  = xct[(size_t)d * L_SEQ + l0 + lane];
  float zv  = zt[(size_t)d * L_SEQ + l0 + lane];
  float dtxv = dtv * xv;
  float s = 0.f;
  for (int cc = 0; cc < c; ++cc) {
    float P = __expf(A * dts[cc * DI + d]);
    s = fmaf(P, s, send[((size_t)cc * DI + d) * DS + lane]);
  }
  const float* pB = xdblBC + (size_t)l0 * NBC + lane;
  float yv = 0.f;
#pragma unroll
  for (int sb = 0; sb < 4; ++sb) {
    float P[16];
#pragma unroll
    for (int j = 0; j < 16; ++j) {
      int t = sb * 16 + j;
      float dt_c  = lane_read(dtv, t);
      float dtx_c = lane_read(dtxv, t);
      float B_c   = pB[(size_t)t * NBC];
      float C_c   = pB[(size_t)t * NBC + DS];
      float dA = __expf(dt_c * A);
      s = fmaf(dA, s, dtx_c * B_c);
      P[j] = s * C_c;
    }
#pragma unroll
    for (int j = 0; j < 16; ++j) Pb[wid][j][lane] = P[j];
    int t4 = lane >> 2, q = lane & 3;
    const float* row = &Pb[wid][t4][q * 16];
    float part = 0.f;
#pragma unroll
    for (int k = 0; k < 8; ++k) {
      float2 v2 = *(const float2*)(row + 2 * k);
      part += v2.x + v2.y;
    }
    part = bp_add(part, (lane ^ 1) << 2);
    part = bp_add(part, (lane ^ 2) << 2);
    float got = __int_as_float(
        __builtin_amdgcn_ds_bpermute((lane & 15) << 4, __float_as_int(part)));
    yv = ((lane >> 4) == sb) ? got : yv;
  }
  float sig = 1.f / (1.f + __expf(-zv));
  ys[lane][wid] = (yv + xv * Dd) * (zv * sig);
  __syncthreads();
  if (tid < 64) {
    int d0 = (blockIdx.x * 4) % DI;
    short4 o;
    o.x = f2bf(ys[tid][0]); o.y = f2bf(ys[tid][1]);
    o.z = f2bf(ys[tid][2]); o.w = f2bf(ys[tid][3]);
    *(short4*)&y[(size_t)(l0 + tid) * DI + d0] = o;
  }
}

// ---------------------------------------------------------------------------
// out_proj + residual (R10).
// ---------------------------------------------------------------------------
__global__ __launch_bounds__(256) void k_outproj(const short* __restrict__ y,
                                                 const short* __restrict__ wo,
                                                 const float* __restrict__ x,
                                                 float* __restrict__ out) {
  __shared__ float4v red[16 * 64];
  int tid = threadIdx.x, lane = tid & 63, w = tid >> 6;
  float4v v = gemm32_core(y, DI, wo, DI, DI, blockIdx.x, blockIdx.y, lane, w, red);
  int lrow = ((w & 1) << 4) + ((lane >> 4) << 2);
  int lcol = ((w >> 1) << 4) + (lane & 15);
  int row = blockIdx.y * 32 + lrow, col = blockIdx.x * 32 + lcol;
#pragma unroll
  for (int r = 0; r < 4; ++r)
    out[(size_t)(row + r) * DM + col] = v[r] + x[(size_t)(row + r) * DM + col];
}

// ---------------------------------------------------------------------------
// Launcher (7 dispatches)
// ---------------------------------------------------------------------------
extern "C" void kernel_launch(void* const* d_in, const int* in_sizes, int n_in,
                              void* d_out, int out_size, void* d_ws, size_t ws_size,
                              hipStream_t stream) {
  const float* x         = (const float*)d_in[0];
  const float* ln_w      = (const float*)d_in[1];
  const float* ln_b      = (const float*)d_in[2];
  const float* in_proj_w = (const float*)d_in[3];
  const float* conv_w    = (const float*)d_in[4];
  const float* conv_b    = (const float*)d_in[5];
  const float* x_proj_w  = (const float*)d_in[6];
  const float* dt_proj_w = (const float*)d_in[7];
  const float* dt_proj_b = (const float*)d_in[8];
  const float* A_log     = (const float*)d_in[9];
  const float* Dv        = (const float*)d_in[10];
  const float* out_proj_w= (const float*)d_in[11];
  float* out = (float*)d_out;

  float* ws = (float*)d_ws;
  // f32 region
  float* xz_in  = ws;                      // 512*1536 = 786432
  float* zt     = xz_in + 786432;          // 1536*512 (transposed z)
  float* xct    = zt + 786432;             // 1536*512 (transposed conv)
  float* dtt    = xct + 786432;            // 1536*512 (transposed dt)
  float* xdblBC = dtt + 786432;            // 512*128  = 65536
  float* send   = xdblBC + 65536;          // 7*1536*64 = 688128
  float* dts    = send + 688128;           // 10752
  float* fend   = dts + 10752;
  // bf16 region
  short* h_bf   = (short*)fend;            // 393216
  short* wi_bf  = h_bf + 393216;           // 2359296
  short* wo_bf  = wi_bf + 2359296;         // 1179648
  short* wcomb  = wo_bf + 1179648;         // 1664*1536 = 2555904
  short* xc_bf  = wcomb + 2555904;         // 786432
  short* y_bf   = xc_bf + 786432;          // 786432

  // 1. prep: LN + weight cvts + Weff build (LDS-staged wx)
  prep<<<PREP_GRID, 256, 0, stream>>>(x, ln_w, ln_b, h_bf, in_proj_w, wi_bf,
                                      x_proj_w, dt_proj_w, wcomb,
                                      out_proj_w, wo_bf);

  // 2. in_proj: x_in row-major + z transposed
  k_inproj<<<dim3(2 * DI / 32, L_SEQ / 32), 256, 0, stream>>>(h_bf, wi_bf,
                                                              xz_in, zt);

  // 3. conv + SiLU: bf16 row-major + f32 transposed
  conv_silu_kernel<<<dim3(DI / 64, L_SEQ / 32), 256, 0, stream>>>(
      xz_in, conv_w, conv_b, xc_bf, xct);

  // 4. proj2: [B/C | dt] = xconv . Wcomb^T (dt transposed + softplus)
  k_proj2<<<dim3(NP2 / 32, L_SEQ / 32), 256, 0, stream>>>(
      xc_bf, wcomb, xdblBC, dtt, dt_proj_b);

  // 5-6. chunked selective scan
  scan_p1<<<((NC - 1) * DI) / 4, 256, 0, stream>>>(dtt, xct, xdblBC, A_log,
                                                   send, dts);
  scan_p3<<<(NC * DI) / 4, 256, 0, stream>>>(dtt, xct, xdblBC, A_log, Dv, zt,
                                             send, dts, y_bf);

  // 7. out_proj + residual
  k_outproj<<<dim3(DM / 32, L_SEQ / 32), 256, 0, stream>>>(y_bf, wo_bf, x, out);
}